// Round 1
// baseline (778.446 us; speedup 1.0000x reference)
//
#include <hip/hip_runtime.h>

#define NB    128       // batch of initial states
#define NTRAJ 128
#define DD    16        // state dim
#define PP    5
#define HH    64
#define NSTEP 63
#define NN    (NB*NTRAJ)   // 16384
#define FF    38
#define DT    0.00390625f

#define W1S 2056   // 64*32 + 8 floats per net (bank-decorrelating pad)
#define W2S 1032   // 64*16 + 8
#define CWS 136    // 64*2  + 8

__device__ __forceinline__ float fast_tanh(float x) {
    // tanh(x) = 1 - 2/(exp(2x)+1); exp inf/0 limits give +-1 correctly
    float e = __expf(2.0f * x);
    return 1.0f - 2.0f * __builtin_amdgcn_rcpf(e + 1.0f);
}

__device__ __forceinline__ float dot4(float x0, float x1, float x2, float x3,
                                      float4 w, float acc) {
    acc = fmaf(x0, w.x, acc);
    acc = fmaf(x1, w.y, acc);
    acc = fmaf(x2, w.z, acc);
    return fmaf(x3, w.w, acc);
}

__global__ __launch_bounds__(256) void sde_kernel(
    const float* __restrict__ x_real, const float* __restrict__ x_imag,
    const float* __restrict__ params, const float* __restrict__ noise,
    const float* __restrict__ W1, const float* __restrict__ B1,
    const float* __restrict__ W2, const float* __restrict__ B2,
    float* __restrict__ out)
{
    __shared__ float w1x[4 * W1S];   // w1x[k][h][j] = W1[k][1+j][h], j=0..31
    __shared__ float w2x[4 * W2S];   // w2x[k][h*16+d] = W2[k][h][d]
    __shared__ float cwt[4 * CWS];   // per (k,h): {const bias, W1[k][0][h]}
    __shared__ float b2s[64];

    const int tid = threadIdx.x;

    // ---- stage weights into LDS (one-time) ----
    {
        const int k = tid >> 6, h = tid & 63;
        #pragma unroll
        for (int j = 0; j < 32; ++j)
            w1x[k * W1S + h * 32 + j] = W1[(k * FF + 1 + j) * HH + h];
        float cb = B1[k * HH + h];
        #pragma unroll
        for (int p = 0; p < PP; ++p)
            cb += params[p] * W1[(k * FF + 1 + 2 * DD + p) * HH + h];
        cwt[k * CWS + h * 2]     = cb;
        cwt[k * CWS + h * 2 + 1] = W1[(k * FF + 0) * HH + h];
        if (tid < 64) b2s[tid] = B2[tid];
    }
    for (int i = tid; i < 4096; i += 256) {
        int k = i >> 10, r = i & 1023;
        w2x[k * W2S + r] = W2[i];
    }
    __syncthreads();

    // ---- lane decomposition: 4 lanes (one per net k) per trajectory ----
    const int lane = tid & 63;
    const int k    = lane & 3;
    const int wv   = tid >> 6;
    const int traj_local = (wv << 4) | (lane >> 2);       // 0..63 within block
    const int n    = blockIdx.x * 64 + traj_local;        // global trajectory
    const int row  = n & (NB - 1);

    float xr[16], xi[16];
    #pragma unroll
    for (int d = 0; d < 16; ++d) {
        xr[d] = x_real[row * 16 + d];
        xi[d] = x_imag[row * 16 + d];
    }

    const float* __restrict__ w1p = &w1x[k * W1S];
    const float* __restrict__ w2p = &w2x[k * W2S];
    const float* __restrict__ cwp = &cwt[k * CWS];
    const float* __restrict__ nsp = noise + (size_t)n * NSTEP;

    float b2r[16];
    #pragma unroll
    for (int j = 0; j < 16; ++j) b2r[j] = b2s[k * 16 + j];

    const bool oddk = (k & 1);
    const bool hik  = (k & 2);

    for (int s = 0; s < NSTEP; ++s) {
        const float t = (float)s * DT;
        float o[16];
        #pragma unroll
        for (int j = 0; j < 16; ++j) o[j] = b2r[j];

        #pragma unroll 2
        for (int h = 0; h < 64; ++h) {
            float2 cw = *reinterpret_cast<const float2*>(&cwp[h * 2]);
            const float4* wp = reinterpret_cast<const float4*>(&w1p[h * 32]);
            float4 wr0 = wp[0], wr1 = wp[1], wr2 = wp[2], wr3 = wp[3];
            float4 wi0 = wp[4], wi1 = wp[5], wi2 = wp[6], wi3 = wp[7];

            float a0 = fmaf(t, cw.y, cw.x);
            a0 = dot4(xr[0],  xr[1],  xr[2],  xr[3],  wr0, a0);
            float a1 = dot4(xr[4],  xr[5],  xr[6],  xr[7],  wr1, 0.0f);
            float a2 = dot4(xr[8],  xr[9],  xr[10], xr[11], wr2, 0.0f);
            float a3 = dot4(xr[12], xr[13], xr[14], xr[15], wr3, 0.0f);
            a0 = dot4(xi[0],  xi[1],  xi[2],  xi[3],  wi0, a0);
            a1 = dot4(xi[4],  xi[5],  xi[6],  xi[7],  wi1, a1);
            a2 = dot4(xi[8],  xi[9],  xi[10], xi[11], wi2, a2);
            a3 = dot4(xi[12], xi[13], xi[14], xi[15], wi3, a3);
            float th = fast_tanh((a0 + a1) + (a2 + a3));

            const float4* vp = reinterpret_cast<const float4*>(&w2p[h * 16]);
            float4 v0 = vp[0], v1 = vp[1], v2 = vp[2], v3 = vp[3];
            o[0]  = fmaf(th, v0.x, o[0]);   o[1]  = fmaf(th, v0.y, o[1]);
            o[2]  = fmaf(th, v0.z, o[2]);   o[3]  = fmaf(th, v0.w, o[3]);
            o[4]  = fmaf(th, v1.x, o[4]);   o[5]  = fmaf(th, v1.y, o[5]);
            o[6]  = fmaf(th, v1.z, o[6]);   o[7]  = fmaf(th, v1.w, o[7]);
            o[8]  = fmaf(th, v2.x, o[8]);   o[9]  = fmaf(th, v2.y, o[9]);
            o[10] = fmaf(th, v2.z, o[10]);  o[11] = fmaf(th, v2.w, o[11]);
            o[12] = fmaf(th, v3.x, o[12]);  o[13] = fmaf(th, v3.y, o[13]);
            o[14] = fmaf(th, v3.z, o[14]);  o[15] = fmaf(th, v3.w, o[15]);
        }

        // ---- exchange the 4 nets' outputs across the 4 k-lanes ----
        const float dw  = nsp[s];
        const float ce  = hik ? dw : DT;   // coefficient for {e, od}
        const float cpe = hik ? DT : dw;   // coefficient for {pe, pod}
        #pragma unroll
        for (int j = 0; j < 16; ++j) {
            float t1 = __shfl_xor(o[j], 1);
            float e  = oddk ? t1   : o[j];   // even net of {k, k^1}
            float od = oddk ? o[j] : t1;     // odd  net of {k, k^1}
            float pe  = __shfl_xor(e, 2);    // even net of other pair
            float pod = __shfl_xor(od, 2);
            // xr += dt*net0 + dw*net2 ; xi += dt*net1 + dw*net3
            xr[j] = fmaf(ce, e,  fmaf(cpe, pe,  xr[j]));
            xi[j] = fmaf(ce, od, fmaf(cpe, pod, xi[j]));
        }
    }

    // ---- write out: [N, 2D] = [xr(16) | xi(16)], 8 floats per lane ----
    float4 lo, hi;
    if (k == 0) {
        lo = make_float4(xr[0], xr[1], xr[2],  xr[3]);
        hi = make_float4(xr[4], xr[5], xr[6],  xr[7]);
    } else if (k == 1) {
        lo = make_float4(xr[8], xr[9], xr[10], xr[11]);
        hi = make_float4(xr[12], xr[13], xr[14], xr[15]);
    } else if (k == 2) {
        lo = make_float4(xi[0], xi[1], xi[2],  xi[3]);
        hi = make_float4(xi[4], xi[5], xi[6],  xi[7]);
    } else {
        lo = make_float4(xi[8], xi[9], xi[10], xi[11]);
        hi = make_float4(xi[12], xi[13], xi[14], xi[15]);
    }
    float4* op = reinterpret_cast<float4*>(out + (size_t)n * 32 + k * 8);
    op[0] = lo;
    op[1] = hi;
}

extern "C" void kernel_launch(void* const* d_in, const int* in_sizes, int n_in,
                              void* d_out, int out_size, void* d_ws, size_t ws_size,
                              hipStream_t stream) {
    const float* x_real = (const float*)d_in[0];
    const float* x_imag = (const float*)d_in[1];
    const float* params = (const float*)d_in[2];
    const float* noise  = (const float*)d_in[3];
    const float* W1     = (const float*)d_in[4];
    const float* B1     = (const float*)d_in[5];
    const float* W2     = (const float*)d_in[6];
    const float* B2     = (const float*)d_in[7];
    float* out = (float*)d_out;

    // 256 blocks x 256 threads: 64 trajectories/block, 4 lanes per trajectory
    sde_kernel<<<dim3(256), dim3(256), 0, stream>>>(
        x_real, x_imag, params, noise, W1, B1, W2, B2, out);
}

// Round 2
// 115.181 us; speedup vs baseline: 6.7585x; 6.7585x over previous
//
#include <hip/hip_runtime.h>
#include <stdint.h>

#define NB    128
#define NSTEP 63
#define DT    0.00390625f

typedef __attribute__((ext_vector_type(8))) short bf16x8;
typedef __attribute__((ext_vector_type(4))) float f32x4;

union Frag {
    bf16x8   v;
    uint32_t u[4];
};

__device__ __forceinline__ short f2bf(float f) {
    uint32_t u = __float_as_uint(f);
    u += 0x7FFF + ((u >> 16) & 1);          // round-to-nearest-even
    return (short)(u >> 16);
}

__device__ __forceinline__ uint32_t pk_bf16(float lo, float hi) {
    uint32_t r;
    asm("v_cvt_pk_bf16_f32 %0, %1, %2" : "=v"(r) : "v"(lo), "v"(hi));
    return r;
}

__device__ __forceinline__ float fast_tanh(float x) {
    // tanh(x) = 1 - 2/(exp(2x)+1); exp inf/0 limits give +-1 correctly
    float e = __expf(2.0f * x);
    return 1.0f - 2.0f * __builtin_amdgcn_rcpf(e + 1.0f);
}

// Per wave: 16 trajectories. GEMM1 (swapped): D1[h,traj] = W1x^T x X^T over
// K=32 state features; 16 MFMAs (256 h-columns). GEMM2 (swapped, zero-masked
// block structure): drift/diffusion outputs, rows permuted so each lane ends
// with its own 8 state components. Hidden-index permutation makes GEMM1's
// C-layout accs directly usable as GEMM2 B-fragments (no transpose).
__global__ __launch_bounds__(256) void sde_mfma(
    const float* __restrict__ x_real, const float* __restrict__ x_imag,
    const float* __restrict__ params, const float* __restrict__ noise,
    const float* __restrict__ W1, const float* __restrict__ B1,
    const float* __restrict__ W2, const float* __restrict__ B2,
    float* __restrict__ out)
{
    __shared__ Frag w1a[16 * 64];   // GEMM1 A-frags (W1x^T), per (tile, lane)
    __shared__ Frag w2a[16 * 64];   // GEMM2 A-frags (W2t, zero-masked), per (fh, lane)

    const int tid  = threadIdx.x;
    const int lane = tid & 63;
    const int l15  = lane & 15;
    const int g    = lane >> 4;
    const int wv   = tid >> 6;

    // ---- stage GEMM1 A-fragments: tile t, lane: row=l15 -> W1x column c1=16t+l15,
    //      elem j -> feature 1 + 8g + j ----
    #pragma unroll
    for (int ii = 0; ii < 4; ++ii) {
        const int t  = wv * 4 + ii;
        const int c1 = 16 * t + l15;
        const int net = c1 >> 6, h = c1 & 63;
        Frag f;
        #pragma unroll
        for (int j = 0; j < 8; ++j) {
            const int jf = 8 * g + j;
            f.v[j] = f2bf(W1[(net * 38 + 1 + jf) * 64 + h]);
        }
        w1a[t * 64 + lane] = f;
    }

    // ---- stage GEMM2 A-fragments: fh = phase*8 + dtile*4 + kt ----
    #pragma unroll
    for (int ii = 0; ii < 4; ++ii) {
        const int fh    = wv * 4 + ii;
        const int phase = fh >> 3;          // 0=drift, 1=diffusion
        const int dtile = (fh >> 2) & 1;    // output row-tile
        const int kt    = fh & 3;           // K-tile
        const int row   = l15;
        const int c     = 8 * (row >> 2) + 4 * dtile + (row & 3);  // state comp
        const int net_c = 2 * phase + (c >> 4);
        const int d     = c & 15;
        Frag f;
        #pragma unroll
        for (int j = 0; j < 8; ++j) {
            const int c1f   = 128 * phase + 32 * kt + 16 * (j >> 2) + 4 * g + (j & 3);
            const int net_h = c1f >> 6;
            const float w = (net_h == net_c)
                          ? W2[(net_h * 64 + (c1f & 63)) * 16 + d] : 0.0f;
            f.v[j] = f2bf(w);
        }
        w2a[fh * 64 + lane] = f;
    }
    __syncthreads();

    // ---- per-lane state: 8 consecutive components of trajectory l15 ----
    const int n    = blockIdx.x * 64 + wv * 16 + l15;
    const int xrow = n & (NB - 1);
    const float* __restrict__ xsrc = (g < 2) ? x_real : x_imag;
    float st[8];
    #pragma unroll
    for (int i = 0; i < 8; ++i) st[i] = xsrc[xrow * 16 + (g & 1) * 8 + i];

    // ---- bias + t-coefficient at this lane's C-layout positions ----
    f32x4 biascur[16], wtdt[16];
    #pragma unroll
    for (int t = 0; t < 16; ++t) {
        #pragma unroll
        for (int r = 0; r < 4; ++r) {
            const int c1 = 16 * t + 4 * g + r;
            const int net = c1 >> 6, h = c1 & 63;
            float b = B1[net * 64 + h];
            #pragma unroll
            for (int p = 0; p < 5; ++p)
                b += params[p] * W1[(net * 38 + 33 + p) * 64 + h];
            biascur[t][r] = b;
            wtdt[t][r]    = DT * W1[(net * 38 + 0) * 64 + h];
        }
    }

    // ---- B2 bias as GEMM2 C-in, rows pre-permuted ----
    f32x4 b2a0, b2a1, b2b0, b2b1;
    #pragma unroll
    for (int r = 0; r < 4; ++r) {
        const int c0 = 8 * g + r, c1c = 8 * g + 4 + r;
        b2a0[r] = B2[c0];       b2a1[r] = B2[c1c];
        b2b0[r] = B2[32 + c0];  b2b1[r] = B2[32 + c1c];
    }

    const float* __restrict__ nsp = noise + (size_t)n * NSTEP;
    float dw = nsp[0];

    for (int s = 0; s < NSTEP; ++s) {
        const float dwn = nsp[(s + 1 < NSTEP) ? s + 1 : s];   // prefetch next

        // state -> bf16 B-fragment (k = 8g + i = component index)
        Frag bx;
        bx.u[0] = pk_bf16(st[0], st[1]);
        bx.u[1] = pk_bf16(st[2], st[3]);
        bx.u[2] = pk_bf16(st[4], st[5]);
        bx.u[3] = pk_bf16(st[6], st[7]);

        // GEMM1: 16 independent MFMAs, C-in = bias + t*w_t
        f32x4 acc[16];
        #pragma unroll
        for (int t = 0; t < 16; ++t) {
            const Frag a = w1a[t * 64 + lane];
            acc[t] = __builtin_amdgcn_mfma_f32_16x16x32_bf16(
                a.v, bx.v, biascur[t], 0, 0, 0);
        }

        // advance bias to next t
        #pragma unroll
        for (int t = 0; t < 16; ++t) biascur[t] += wtdt[t];

        // GEMM2: drift (acc tiles 0..7), diffusion (acc tiles 8..15)
        f32x4 da0 = b2a0, da1 = b2a1, db0 = b2b0, db1 = b2b1;
        #pragma unroll
        for (int kt = 0; kt < 4; ++kt) {
            {   // drift: B-frag from tanh(acc[2kt]), tanh(acc[2kt+1])
                const float t0 = fast_tanh(acc[2 * kt][0]);
                const float t1 = fast_tanh(acc[2 * kt][1]);
                const float t2 = fast_tanh(acc[2 * kt][2]);
                const float t3 = fast_tanh(acc[2 * kt][3]);
                const float t4 = fast_tanh(acc[2 * kt + 1][0]);
                const float t5 = fast_tanh(acc[2 * kt + 1][1]);
                const float t6 = fast_tanh(acc[2 * kt + 1][2]);
                const float t7 = fast_tanh(acc[2 * kt + 1][3]);
                Frag pb;
                pb.u[0] = pk_bf16(t0, t1);  pb.u[1] = pk_bf16(t2, t3);
                pb.u[2] = pk_bf16(t4, t5);  pb.u[3] = pk_bf16(t6, t7);
                const Frag a0 = w2a[(0 + kt) * 64 + lane];
                const Frag a1 = w2a[(4 + kt) * 64 + lane];
                da0 = __builtin_amdgcn_mfma_f32_16x16x32_bf16(a0.v, pb.v, da0, 0, 0, 0);
                da1 = __builtin_amdgcn_mfma_f32_16x16x32_bf16(a1.v, pb.v, da1, 0, 0, 0);
            }
            {   // diffusion: B-frag from tanh(acc[8+2kt]), tanh(acc[8+2kt+1])
                const float t0 = fast_tanh(acc[8 + 2 * kt][0]);
                const float t1 = fast_tanh(acc[8 + 2 * kt][1]);
                const float t2 = fast_tanh(acc[8 + 2 * kt][2]);
                const float t3 = fast_tanh(acc[8 + 2 * kt][3]);
                const float t4 = fast_tanh(acc[8 + 2 * kt + 1][0]);
                const float t5 = fast_tanh(acc[8 + 2 * kt + 1][1]);
                const float t6 = fast_tanh(acc[8 + 2 * kt + 1][2]);
                const float t7 = fast_tanh(acc[8 + 2 * kt + 1][3]);
                Frag pb;
                pb.u[0] = pk_bf16(t0, t1);  pb.u[1] = pk_bf16(t2, t3);
                pb.u[2] = pk_bf16(t4, t5);  pb.u[3] = pk_bf16(t6, t7);
                const Frag a0 = w2a[(8 + kt) * 64 + lane];
                const Frag a1 = w2a[(12 + kt) * 64 + lane];
                db0 = __builtin_amdgcn_mfma_f32_16x16x32_bf16(a0.v, pb.v, db0, 0, 0, 0);
                db1 = __builtin_amdgcn_mfma_f32_16x16x32_bf16(a1.v, pb.v, db1, 0, 0, 0);
            }
        }

        // Euler-Maruyama update: x += a*dt + b*dw (all lane-local)
        #pragma unroll
        for (int i = 0; i < 4; ++i) {
            st[i]     = fmaf(DT, da0[i], fmaf(dw, db0[i], st[i]));
            st[i + 4] = fmaf(DT, da1[i], fmaf(dw, db1[i], st[i + 4]));
        }
        dw = dwn;
    }

    // ---- write out: lane holds comps 8g..8g+7 of traj n ----
    float4* op = reinterpret_cast<float4*>(out + (size_t)n * 32 + 8 * g);
    op[0] = make_float4(st[0], st[1], st[2], st[3]);
    op[1] = make_float4(st[4], st[5], st[6], st[7]);
}

extern "C" void kernel_launch(void* const* d_in, const int* in_sizes, int n_in,
                              void* d_out, int out_size, void* d_ws, size_t ws_size,
                              hipStream_t stream) {
    const float* x_real = (const float*)d_in[0];
    const float* x_imag = (const float*)d_in[1];
    const float* params = (const float*)d_in[2];
    const float* noise  = (const float*)d_in[3];
    const float* W1     = (const float*)d_in[4];
    const float* B1     = (const float*)d_in[5];
    const float* W2     = (const float*)d_in[6];
    const float* B2     = (const float*)d_in[7];
    float* out = (float*)d_out;

    // 256 blocks x 256 threads: 4 waves/block, 16 trajectories/wave
    sde_mfma<<<dim3(256), dim3(256), 0, stream>>>(
        x_real, x_imag, params, noise, W1, B1, W2, B2, out);
}

// Round 4
// 83.430 us; speedup vs baseline: 9.3305x; 1.3806x over previous
//
#include <hip/hip_runtime.h>
#include <stdint.h>

#define NB    128
#define NSTEP 63
#define DT    0.00390625f
#define TSC   2.8853900817779268f   // 2*log2(e): folded into GEMM1 weights

typedef __attribute__((ext_vector_type(8))) short bf16x8;
typedef __attribute__((ext_vector_type(4))) float f32x4;

union Frag { bf16x8 v; uint32_t u[4]; };

__device__ __forceinline__ short f2bf(float f) {
    uint32_t u = __float_as_uint(f);
    u += 0x7FFF + ((u >> 16) & 1);          // round-to-nearest-even
    return (short)(u >> 16);
}

__device__ __forceinline__ uint32_t pk_bf16(float lo, float hi) {
    uint32_t r;
    asm("v_cvt_pk_bf16_f32 %0, %1, %2" : "=v"(r) : "v"(lo), "v"(hi));
    return r;
}

// y = 2*log2e*preact (scale folded into weights): tanh = 1 - 2/(2^y + 1).
// NOTE: must use the exp2 BUILTIN, not inline asm — v_exp_f32 is a TRANS op
// with a required wait-state before dependent VALU reads; the hazard
// recognizer can't see inside inline asm (round-3 failure: state explosion).
__device__ __forceinline__ float tanh_sc(float y) {
    float e = __builtin_amdgcn_exp2f(y);
    return fmaf(-2.0f, __builtin_amdgcn_rcpf(e + 1.0f), 1.0f);
}

// Block = 256 threads = 4 waves = one 16-trajectory group; wave wv owns net wv.
// GEMM1 (swapped): wave's 64 hidden cols, 4 MFMAs; GEMM2 (swapped, dense,
// K=64): net's 16 outputs, 2 MFMAs. Hidden-order permutation makes GEMM1's
// C-layout registers bit-identical to GEMM2's B-fragment slots (lane-local).
// Cross-net output exchange via double-buffered LDS, 1 barrier/step; all
// waves read identical addresses -> bitwise-identical replicated state.
__global__ __launch_bounds__(256, 4) void sde_mfma4(
    const float* __restrict__ x_real, const float* __restrict__ x_imag,
    const float* __restrict__ params, const float* __restrict__ noise,
    const float* __restrict__ W1, const float* __restrict__ B1,
    const float* __restrict__ W2, const float* __restrict__ B2,
    float* __restrict__ out)
{
    // [dbuf][net 4][traj 16][20 floats: d 0..15 used, pad 4]
    __shared__ __attribute__((aligned(16))) float xbuf[2][4][16][20];

    const int tid  = threadIdx.x;
    const int lane = tid & 63;
    const int l15  = lane & 15;
    const int g    = lane >> 4;
    const int wv   = tid >> 6;          // net index 0..3

    // ---- GEMM1 A-frags: tile t, row=l15 -> h = 16t + l15 (within net wv),
    //      elem j -> state feature 8g + j; pre-scaled by TSC ----
    Frag w1f[4];
    #pragma unroll
    for (int t = 0; t < 4; ++t) {
        const int h = 16 * t + l15;
        #pragma unroll
        for (int j = 0; j < 8; ++j)
            w1f[t].v[j] = f2bf(TSC * W1[(wv * 38 + 1 + 8 * g + j) * 64 + h]);
    }

    // ---- GEMM2 A-frags: row=l15=d, elem j -> h_local = 16*(2kt+(j>>2)) + 4g + (j&3) ----
    Frag w2f[2];
    #pragma unroll
    for (int kt = 0; kt < 2; ++kt) {
        #pragma unroll
        for (int j = 0; j < 8; ++j) {
            const int hl = 16 * (2 * kt + (j >> 2)) + 4 * g + (j & 3);
            w2f[kt].v[j] = f2bf(W2[(wv * 64 + hl) * 16 + l15]);
        }
    }

    // ---- bias + t-coefficient at C-layout positions (scaled by TSC) ----
    float pr[5];
    #pragma unroll
    for (int p = 0; p < 5; ++p) pr[p] = params[p];
    f32x4 biascur[4], wtdt[4];
    #pragma unroll
    for (int t = 0; t < 4; ++t) {
        #pragma unroll
        for (int r = 0; r < 4; ++r) {
            const int h = 16 * t + 4 * g + r;
            float b = B1[wv * 64 + h];
            #pragma unroll
            for (int p = 0; p < 5; ++p)
                b = fmaf(pr[p], W1[(wv * 38 + 33 + p) * 64 + h], b);
            biascur[t][r] = TSC * b;
            wtdt[t][r]    = (TSC * DT) * W1[(wv * 38 + 0) * 64 + h];
        }
    }

    // ---- B2 C-in: row 4g+r = output dim d ----
    f32x4 bc;
    #pragma unroll
    for (int r = 0; r < 4; ++r) bc[r] = B2[wv * 16 + 4 * g + r];

    // ---- state: lane holds comps 8g..8g+7 of traj n (replicated across waves) ----
    const int n    = blockIdx.x * 16 + l15;
    const int xrow = n & (NB - 1);
    const float* __restrict__ xsrc = (g < 2) ? x_real : x_imag;
    float st[8];
    #pragma unroll
    for (int i = 0; i < 8; ++i) st[i] = xsrc[xrow * 16 + (g & 1) * 8 + i];

    const float* __restrict__ nsp = noise + (size_t)n * NSTEP;
    float dw = nsp[0];

    float* wrp           = &xbuf[0][wv][l15][4 * g];
    const float* rd_dr   = &xbuf[0][g >> 1][l15][8 * (g & 1)];
    const float* rd_df   = &xbuf[0][2 + (g >> 1)][l15][8 * (g & 1)];
    const int dstep = 4 * 16 * 20;   // floats per dbuf half

    for (int s = 0; s < NSTEP; ++s) {
        const float dwn = nsp[(s + 1 < NSTEP) ? s + 1 : s];

        // state -> bf16 B-fragment (k-slot 8g+j = component 8g+j)
        Frag bx;
        bx.u[0] = pk_bf16(st[0], st[1]);
        bx.u[1] = pk_bf16(st[2], st[3]);
        bx.u[2] = pk_bf16(st[4], st[5]);
        bx.u[3] = pk_bf16(st[6], st[7]);

        // GEMM1: 4 MFMAs, C-in = scaled bias + t*w_t
        f32x4 acc[4];
        #pragma unroll
        for (int t = 0; t < 4; ++t)
            acc[t] = __builtin_amdgcn_mfma_f32_16x16x32_bf16(
                w1f[t].v, bx.v, biascur[t], 0, 0, 0);
        #pragma unroll
        for (int t = 0; t < 4; ++t) biascur[t] += wtdt[t];

        // GEMM2: K=64 over own net's hidden, output = own net's 16 dims
        f32x4 o = bc;
        #pragma unroll
        for (int kt = 0; kt < 2; ++kt) {
            const float t0 = tanh_sc(acc[2 * kt][0]);
            const float t1 = tanh_sc(acc[2 * kt][1]);
            const float t2 = tanh_sc(acc[2 * kt][2]);
            const float t3 = tanh_sc(acc[2 * kt][3]);
            const float t4 = tanh_sc(acc[2 * kt + 1][0]);
            const float t5 = tanh_sc(acc[2 * kt + 1][1]);
            const float t6 = tanh_sc(acc[2 * kt + 1][2]);
            const float t7 = tanh_sc(acc[2 * kt + 1][3]);
            Frag pb;
            pb.u[0] = pk_bf16(t0, t1);  pb.u[1] = pk_bf16(t2, t3);
            pb.u[2] = pk_bf16(t4, t5);  pb.u[3] = pk_bf16(t6, t7);
            o = __builtin_amdgcn_mfma_f32_16x16x32_bf16(w2f[kt].v, pb.v, o, 0, 0, 0);
        }

        // ---- exchange: write own net's 4 outputs, read all 4 nets ----
        const int db = s & 1;
        *reinterpret_cast<f32x4*>(wrp + db * dstep) = o;
        __syncthreads();
        const float* dp = rd_dr + db * dstep;
        const float* fp = rd_df + db * dstep;
        const f32x4 dr0 = *reinterpret_cast<const f32x4*>(dp);
        const f32x4 dr1 = *reinterpret_cast<const f32x4*>(dp + 4);
        const f32x4 df0 = *reinterpret_cast<const f32x4*>(fp);
        const f32x4 df1 = *reinterpret_cast<const f32x4*>(fp + 4);

        #pragma unroll
        for (int i = 0; i < 4; ++i) {
            st[i]     = fmaf(DT, dr0[i], fmaf(dw, df0[i], st[i]));
            st[i + 4] = fmaf(DT, dr1[i], fmaf(dw, df1[i], st[i + 4]));
        }
        dw = dwn;
    }

    // ---- write out (wave 0 only): lane holds comps 8g..8g+7 of traj n ----
    if (wv == 0) {
        float4* op = reinterpret_cast<float4*>(out + (size_t)n * 32 + 8 * g);
        op[0] = make_float4(st[0], st[1], st[2], st[3]);
        op[1] = make_float4(st[4], st[5], st[6], st[7]);
    }
}

extern "C" void kernel_launch(void* const* d_in, const int* in_sizes, int n_in,
                              void* d_out, int out_size, void* d_ws, size_t ws_size,
                              hipStream_t stream) {
    const float* x_real = (const float*)d_in[0];
    const float* x_imag = (const float*)d_in[1];
    const float* params = (const float*)d_in[2];
    const float* noise  = (const float*)d_in[3];
    const float* W1     = (const float*)d_in[4];
    const float* B1     = (const float*)d_in[5];
    const float* W2     = (const float*)d_in[6];
    const float* B2     = (const float*)d_in[7];
    float* out = (float*)d_out;

    // 1024 blocks x 256 threads: 4 waves/block, one 16-traj group per block
    sde_mfma4<<<dim3(1024), dim3(256), 0, stream>>>(
        x_real, x_imag, params, noise, W1, B1, W2, B2, out);
}